// Round 1
// baseline (3522.622 us; speedup 1.0000x reference)
//
#include <hip/hip_runtime.h>
#include <stdint.h>

// TinyGRU: 2-layer GRU (B=512,S=1024,I=64,H=128) + FC(128->10) on last step.
// Strategy: one block per batch chain (512 independent recurrences, no grid
// sync). Weights converted to f16 and held in per-thread REGISTERS (reused
// 1024x); dots via v_dot2_f32_f16 (fp32 accumulate); gate math fp32; h stored
// to LDS as f16 each step for the broadcast dot reads. G=2 gate rows per
// thread balances LDS-return BW (256B/clk) against VALU dot throughput.

typedef _Float16 half_t;
typedef _Float16 v2h __attribute__((ext_vector_type(2)));
typedef _Float16 v8h __attribute__((ext_vector_type(8)));

#define BB 512
#define SS 1024
#define II 64
#define HH 128

union V8U { v8h v; v2h h2[4]; };

__device__ __forceinline__ float dot2acc(v2h a, v2h b, float c) {
    return __builtin_amdgcn_fdot2(a, b, c, false);
}
__device__ __forceinline__ float sigmoidf_(float x) {
    return 1.0f / (1.0f + __expf(-x));
}
__device__ __forceinline__ float tanhf_(float x) {
    // tanh(x) = 1 - 2/(exp(2x)+1); saturates correctly at +-inf
    return 1.0f - 2.0f / (1.0f + __expf(2.0f * x));
}

// ---------------- Layer 0: I=64 -> H=128, writes h1 [B,S,128] as f16 --------
// 192 threads: thread m owns gate rows m and m+192 (full K). Weights in regs:
// 2*(32+64)=192 dwords of packed f16.
__global__ __launch_bounds__(192, 2)
void gru_layer0(const float* __restrict__ x,    // [B,S,64]
                const float* __restrict__ Wih,  // [384,64]
                const float* __restrict__ Whh,  // [384,128]
                const float* __restrict__ bih,
                const float* __restrict__ bhh,
                half_t* __restrict__ h1out)     // [B,S,128] f16
{
    const int b   = blockIdx.x;
    const int tid = threadIdx.x;
    const int r0  = tid;         // rows 0..191   (r gates 0..127, z gates 0..63)
    const int r1  = tid + 192;   // rows 192..383 (z gates 64..127, n gates 0..127)

    __shared__ alignas(16) half_t s_x[2][II];   // double-buffered x_t (f16)
    __shared__ alignas(16) half_t s_h[HH];      // h_{t-1} (f16)
    __shared__ float s_p[256];                  // r/z rows: gi+gh
    __shared__ float s_ni[HH], s_nh[HH];        // n rows: gi, gh separate

    // ---- load weights into registers as packed f16 pairs ----
    v2h wih0[32], wih1[32], whh0[64], whh1[64];
    {
        const float2* p0 = (const float2*)(Wih + r0 * II);
        const float2* p1 = (const float2*)(Wih + r1 * II);
#pragma unroll
        for (int k = 0; k < 32; ++k) {
            float2 a = p0[k]; wih0[k] = v2h{(half_t)a.x, (half_t)a.y};
            float2 c = p1[k]; wih1[k] = v2h{(half_t)c.x, (half_t)c.y};
        }
        const float2* q0 = (const float2*)(Whh + r0 * HH);
        const float2* q1 = (const float2*)(Whh + r1 * HH);
#pragma unroll
        for (int k = 0; k < 64; ++k) {
            float2 a = q0[k]; whh0[k] = v2h{(half_t)a.x, (half_t)a.y};
            float2 c = q1[k]; whh1[k] = v2h{(half_t)c.x, (half_t)c.y};
        }
    }
    const float bi0 = bih[r0], bh0 = bhh[r0];
    const float bi1 = bih[r1], bh1 = bhh[r1];

    float hreg = 0.0f;                 // threads 0..127 own h[m]
    if (tid < HH) s_h[tid] = (half_t)0.0f;
    const float* xb = x + (size_t)b * SS * II;
    if (tid >= 128) s_x[0][tid - 128] = (half_t)xb[tid - 128];  // stage t=0
    __syncthreads();

    half_t* hb = h1out + (size_t)b * SS * HH;

    for (int t = 0; t < SS; ++t) {
        // -------- phase 1: all 384 gate-row dots (2 rows/thread) --------
        float xpf = 0.0f;
        const bool pf = (tid >= 128) && (t + 1 < SS);
        if (pf) xpf = xb[(t + 1) * II + (tid - 128)];   // prefetch next x

        float ai0 = bi0, ah0 = bh0, ai1 = bi1, ah1 = bh1;
        const v8h* xv8 = (const v8h*)s_x[t & 1];
        const v8h* hv8 = (const v8h*)s_h;
#pragma unroll
        for (int k = 0; k < 8; ++k) {           // x-part: 64 f16
            V8U u; u.v = xv8[k];
#pragma unroll
            for (int j = 0; j < 4; ++j) {
                ai0 = dot2acc(u.h2[j], wih0[4 * k + j], ai0);
                ai1 = dot2acc(u.h2[j], wih1[4 * k + j], ai1);
            }
        }
#pragma unroll
        for (int k = 0; k < 16; ++k) {          // h-part: 128 f16
            V8U u; u.v = hv8[k];
#pragma unroll
            for (int j = 0; j < 4; ++j) {
                ah0 = dot2acc(u.h2[j], whh0[4 * k + j], ah0);
                ah1 = dot2acc(u.h2[j], whh1[4 * k + j], ah1);
            }
        }
        s_p[r0] = ai0 + ah0;                    // rows 0..191 are r/z rows
        if (r1 < 256) {                         // wave-uniform (tid<64)
            s_p[r1] = ai1 + ah1;
        } else {
            s_ni[r1 - 256] = ai1;
            s_nh[r1 - 256] = ah1;
        }
        if (pf) s_x[(t + 1) & 1][tid - 128] = (half_t)xpf;
        __syncthreads();

        // -------- phase 2: gate combine by threads 0..127 --------
        if (tid < HH) {
            float r = sigmoidf_(s_p[tid]);
            float z = sigmoidf_(s_p[tid + 128]);
            float n = tanhf_(s_ni[tid] + r * s_nh[tid]);
            hreg = (1.0f - z) * n + z * hreg;
            half_t hh = (half_t)hreg;
            s_h[tid] = hh;
            hb[t * HH + tid] = hh;
        }
        __syncthreads();
    }
}

// ---------------- Layer 1: I=128 -> H=128, consumes h1 f16, emits FC --------
// 384 threads: (m, kh) = (tid%192, tid/192). Thread owns rows m, m+192 over
// k-half kh (64 of 128). Weights in regs: 2*(32+32)=128 dwords of packed f16.
__global__ __launch_bounds__(384, 2)
void gru_layer1(const half_t* __restrict__ h1,  // [B,S,128] f16
                const float* __restrict__ Wih,  // [384,128]
                const float* __restrict__ Whh,  // [384,128]
                const float* __restrict__ bih,
                const float* __restrict__ bhh,
                const float* __restrict__ fcw,  // [10,128]
                const float* __restrict__ fcb,  // [10]
                float* __restrict__ out)        // [B,10]
{
    const int b   = blockIdx.x;
    const int tid = threadIdx.x;
    const int kh  = tid / 192;          // k-half: 0 or 1 (wave-uniform)
    const int m   = tid - kh * 192;
    const int r0  = m, r1 = m + 192;

    __shared__ alignas(16) uint32_t s_x[2][64]; // staged h1[t] as packed f16x2
    __shared__ alignas(16) half_t s_h[HH];
    __shared__ float s_p[2][256];               // r/z partials per k-half
    __shared__ float s_ni[2][HH], s_nh[2][HH];  // n partials per k-half
    __shared__ float s_hf[HH];                  // final h for FC

    v2h wih0[32], wih1[32], whh0[32], whh1[32];
    {
        const float2* p0 = (const float2*)(Wih + r0 * HH + kh * 64);
        const float2* p1 = (const float2*)(Wih + r1 * HH + kh * 64);
#pragma unroll
        for (int k = 0; k < 32; ++k) {
            float2 a = p0[k]; wih0[k] = v2h{(half_t)a.x, (half_t)a.y};
            float2 c = p1[k]; wih1[k] = v2h{(half_t)c.x, (half_t)c.y};
        }
        const float2* q0 = (const float2*)(Whh + r0 * HH + kh * 64);
        const float2* q1 = (const float2*)(Whh + r1 * HH + kh * 64);
#pragma unroll
        for (int k = 0; k < 32; ++k) {
            float2 a = q0[k]; whh0[k] = v2h{(half_t)a.x, (half_t)a.y};
            float2 c = q1[k]; whh1[k] = v2h{(half_t)c.x, (half_t)c.y};
        }
    }
    // biases folded into kh==0 partials only
    const float bi0 = (kh == 0) ? bih[r0] : 0.0f;
    const float bh0 = (kh == 0) ? bhh[r0] : 0.0f;
    const float bi1 = (kh == 0) ? bih[r1] : 0.0f;
    const float bh1 = (kh == 0) ? bhh[r1] : 0.0f;

    float hreg = 0.0f;
    if (tid < HH) s_h[tid] = (half_t)0.0f;
    const uint32_t* xb = (const uint32_t*)(h1 + (size_t)b * SS * HH); // 64 dwords/step
    if (tid >= 192 && tid < 256) s_x[0][tid - 192] = xb[tid - 192];   // stage t=0
    __syncthreads();

    for (int t = 0; t < SS; ++t) {
        // -------- phase 1 --------
        uint32_t xpf = 0u;
        const bool pf = (tid >= 192 && tid < 256) && (t + 1 < SS);
        if (pf) xpf = xb[(t + 1) * 64 + (tid - 192)];

        float ai0 = bi0, ah0 = bh0, ai1 = bi1, ah1 = bh1;
        const v8h* xv8 = (const v8h*)(&s_x[t & 1][kh * 32]); // my 64-elem k-half
        const v8h* hv8 = (const v8h*)(&s_h[kh * 64]);
#pragma unroll
        for (int k = 0; k < 8; ++k) {           // x-part half: 64 f16
            V8U u; u.v = xv8[k];
#pragma unroll
            for (int j = 0; j < 4; ++j) {
                ai0 = dot2acc(u.h2[j], wih0[4 * k + j], ai0);
                ai1 = dot2acc(u.h2[j], wih1[4 * k + j], ai1);
            }
        }
#pragma unroll
        for (int k = 0; k < 8; ++k) {           // h-part half: 64 f16
            V8U u; u.v = hv8[k];
#pragma unroll
            for (int j = 0; j < 4; ++j) {
                ah0 = dot2acc(u.h2[j], whh0[4 * k + j], ah0);
                ah1 = dot2acc(u.h2[j], whh1[4 * k + j], ah1);
            }
        }
        s_p[kh][r0] = ai0 + ah0;                // rows 0..191: r/z
        if (r1 < 256) {                         // wave-uniform (m<64)
            s_p[kh][r1] = ai1 + ah1;
        } else {
            s_ni[kh][r1 - 256] = ai1;
            s_nh[kh][r1 - 256] = ah1;
        }
        if (pf) s_x[(t + 1) & 1][tid - 192] = xpf;
        __syncthreads();

        // -------- phase 2 --------
        if (tid < HH) {
            float r = sigmoidf_(s_p[0][tid] + s_p[1][tid]);
            float z = sigmoidf_(s_p[0][tid + 128] + s_p[1][tid + 128]);
            float ni = s_ni[0][tid] + s_ni[1][tid];
            float nh = s_nh[0][tid] + s_nh[1][tid];
            float n = tanhf_(ni + r * nh);
            hreg = (1.0f - z) * n + z * hreg;
            s_h[tid] = (half_t)hreg;
        }
        __syncthreads();
    }

    // -------- FC epilogue: out[b,c] = fc_w[c,:] . h_final + fc_b[c] --------
    if (tid < HH) s_hf[tid] = hreg;
    __syncthreads();
    if (tid < 10) {
        float acc = fcb[tid];
        const float* wr = fcw + tid * HH;
#pragma unroll 8
        for (int k = 0; k < HH; ++k) acc += wr[k] * s_hf[k];
        out[b * 10 + tid] = acc;
    }
}

extern "C" void kernel_launch(void* const* d_in, const int* in_sizes, int n_in,
                              void* d_out, int out_size, void* d_ws, size_t ws_size,
                              hipStream_t stream) {
    const float* x    = (const float*)d_in[0];
    const float* Wih0 = (const float*)d_in[1];
    const float* Whh0 = (const float*)d_in[2];
    const float* bih0 = (const float*)d_in[3];
    const float* bhh0 = (const float*)d_in[4];
    const float* Wih1 = (const float*)d_in[5];
    const float* Whh1 = (const float*)d_in[6];
    const float* bih1 = (const float*)d_in[7];
    const float* bhh1 = (const float*)d_in[8];
    const float* fcw  = (const float*)d_in[9];
    const float* fcb  = (const float*)d_in[10];

    half_t* h1 = (half_t*)d_ws;  // [512,1024,128] f16 = 134 MB scratch

    gru_layer0<<<BB, 192, 0, stream>>>(x, Wih0, Whh0, bih0, bhh0, h1);
    gru_layer1<<<BB, 384, 0, stream>>>(h1, Wih1, Whh1, bih1, bhh1, fcw, fcb,
                                       (float*)d_out);
}

// Round 2
// 1697.325 us; speedup vs baseline: 2.0754x; 2.0754x over previous
//
#include <hip/hip_runtime.h>
#include <stdint.h>

// TinyGRU via MFMA: 16 chains/block (32 blocks), each step is a
// [16x128]x[128x384] GEMM on the matrix pipe (v_mfma_f32_16x16x32_f16).
// Wave w owns h-slice [16w,16w+16) and its 3 gate tiles (r,z,n): D-layout
// (col=lane&15=gate-row, row=quad*4+reg=chain) puts r,z,n for one (chain,h)
// in the SAME lane -> gate math fully in-register, no D round-trip.
// h double-buffered in LDS as f16 [16][136] (stride 17x16B, balanced banks);
// one barrier per step. Weights in register B-fragments, reused 1024x.

typedef _Float16 half_t;
typedef _Float16 half8 __attribute__((ext_vector_type(8)));
typedef float f32x4 __attribute__((ext_vector_type(4)));

#define SS 1024
#define CPB 16           // chains per block
#define NBLK 32          // 512 / CPB
#define HST 136          // padded LDS row stride for 128-wide (f16 elems)
#define XST 72           // padded LDS row stride for 64-wide (f16 elems)

#define MFMA16(a, b, c) __builtin_amdgcn_mfma_f32_16x16x32_f16(a, b, c, 0, 0, 0)

__device__ __forceinline__ float sigmoidf_(float x) {
    return __builtin_amdgcn_rcpf(1.0f + __expf(-x));
}
__device__ __forceinline__ float tanhf_(float x) {
    return 1.0f - 2.0f * __builtin_amdgcn_rcpf(1.0f + __expf(2.0f * x));
}
// load 8 consecutive floats, convert to packed f16 B-fragment
__device__ __forceinline__ half8 cvt8(const float* p) {
    f32x4 a = *(const f32x4*)p;
    f32x4 b = *(const f32x4*)(p + 4);
    half8 r;
    r[0] = (half_t)a[0]; r[1] = (half_t)a[1]; r[2] = (half_t)a[2]; r[3] = (half_t)a[3];
    r[4] = (half_t)b[0]; r[5] = (half_t)b[1]; r[6] = (half_t)b[2]; r[7] = (half_t)b[3];
    return r;
}

// ---------------- Layer 0: x[B,S,64] f32 -> h1[B,S,128] f16 ----------------
__global__ __launch_bounds__(512, 2)
void gru_rec0(const float* __restrict__ x, const float* __restrict__ Wih,
              const float* __restrict__ Whh, const float* __restrict__ bih,
              const float* __restrict__ bhh, half_t* __restrict__ h1)
{
    const int tid  = threadIdx.x;
    const int w    = tid >> 6;          // wave = h-slice 0..7
    const int lane = tid & 63;
    const int quad = lane >> 4;
    const int col  = lane & 15;
    const int cb   = blockIdx.x * CPB;

    __shared__ alignas(16) half_t s_x[2][CPB * XST];
    __shared__ alignas(16) half_t s_h[2][CPB * HST];

    // ---- B-fragments: lane holds W[16w+col][quad*8 + s*32 + 0..7] ----
    const int rr = w * 16 + col;        // this lane's gate-row (within gate)
    half8 Bxr[2], Bxz[2], Bxn[2];       // Wih (K=64 -> 2 k-slices)
    half8 Bhr[4], Bhz[4], Bhn[4];       // Whh (K=128 -> 4 k-slices)
#pragma unroll
    for (int s = 0; s < 2; ++s) {
        Bxr[s] = cvt8(Wih + (rr      ) * 64 + s * 32 + quad * 8);
        Bxz[s] = cvt8(Wih + (rr + 128) * 64 + s * 32 + quad * 8);
        Bxn[s] = cvt8(Wih + (rr + 256) * 64 + s * 32 + quad * 8);
    }
#pragma unroll
    for (int s = 0; s < 4; ++s) {
        Bhr[s] = cvt8(Whh + (rr      ) * 128 + s * 32 + quad * 8);
        Bhz[s] = cvt8(Whh + (rr + 128) * 128 + s * 32 + quad * 8);
        Bhn[s] = cvt8(Whh + (rr + 256) * 128 + s * 32 + quad * 8);
    }
    const float br  = bih[rr] + bhh[rr];
    const float bz  = bih[128 + rr] + bhh[128 + rr];
    const float bni = bih[256 + rr];
    const float bnh = bhh[256 + rr];

    // zero h buffer 0 (h0 = 0)
    for (int i = tid; i < CPB * HST; i += 512) s_h[0][i] = (half_t)0.0f;

    // staging: 512 threads, thread -> (chain sm, 2 x-cols sc2)
    const int sm  = tid >> 5;
    const int sc2 = (tid & 31) * 2;
    const float* xrow = x + (size_t)(cb + sm) * SS * 64 + sc2;
    {   // stage x_0
        float2 g = *(const float2*)(xrow);
        s_x[0][sm * XST + sc2]     = (half_t)g.x;
        s_x[0][sm * XST + sc2 + 1] = (half_t)g.y;
    }
    __syncthreads();

    // copy-out mapping: thread -> (chain sm, 4 h-cols sc4)
    const int sc4 = (tid & 31) * 4;
    half_t* h1row = h1 + (size_t)(cb + sm) * SS * 128 + sc4;

    float hp[4] = {0.f, 0.f, 0.f, 0.f};   // h_prev for chains quad*4+i at col hcol
    const int hcol = w * 16 + col;

    for (int t = 0; t < SS; ++t) {
        const int cur = t & 1, nxt = cur ^ 1;

        float2 g = {0.f, 0.f};
        const bool pf = (t + 1 < SS);
        if (pf) g = *(const float2*)(xrow + (size_t)(t + 1) * 64);

        if (t >= 1) {   // write h_{t-1} (stable in s_h[cur]) to global
            uint2 hv = *(const uint2*)(&s_h[cur][sm * HST + sc4]);
            *(uint2*)(h1row + (size_t)(t - 1) * 128) = hv;
        }

        f32x4 ar  = {br, br, br, br},     az  = {bz, bz, bz, bz};
        f32x4 ani = {bni, bni, bni, bni}, anh = {bnh, bnh, bnh, bnh};
#pragma unroll
        for (int s = 0; s < 2; ++s) {    // x-contribution (K=64)
            half8 ax = *(const half8*)(&s_x[cur][col * XST + s * 32 + quad * 8]);
            ar  = MFMA16(ax, Bxr[s], ar);
            az  = MFMA16(ax, Bxz[s], az);
            ani = MFMA16(ax, Bxn[s], ani);
        }
#pragma unroll
        for (int s = 0; s < 4; ++s) {    // h-contribution (K=128)
            half8 ah = *(const half8*)(&s_h[cur][col * HST + s * 32 + quad * 8]);
            ar  = MFMA16(ah, Bhr[s], ar);
            az  = MFMA16(ah, Bhz[s], az);
            anh = MFMA16(ah, Bhn[s], anh);
        }
#pragma unroll
        for (int i = 0; i < 4; ++i) {    // gates in-register; chain = quad*4+i
            float r = sigmoidf_(ar[i]);
            float z = sigmoidf_(az[i]);
            float n = tanhf_(ani[i] + r * anh[i]);
            float h = (1.0f - z) * n + z * hp[i];
            hp[i] = h;
            s_h[nxt][(quad * 4 + i) * HST + hcol] = (half_t)h;
        }
        if (pf) {
            s_x[nxt][sm * XST + sc2]     = (half_t)g.x;
            s_x[nxt][sm * XST + sc2 + 1] = (half_t)g.y;
        }
        __syncthreads();
    }
    {   // final copy-out: h_{1023} sits in s_h[0]
        uint2 hv = *(const uint2*)(&s_h[0][sm * HST + sc4]);
        *(uint2*)(h1row + (size_t)(SS - 1) * 128) = hv;
    }
}

// ------------- Layer 1: h1[B,S,128] f16 -> FC -> out[B,10] f32 -------------
__global__ __launch_bounds__(512, 2)
void gru_rec1(const half_t* __restrict__ h1, const float* __restrict__ Wih,
              const float* __restrict__ Whh, const float* __restrict__ bih,
              const float* __restrict__ bhh, const float* __restrict__ fcw,
              const float* __restrict__ fcb, float* __restrict__ out)
{
    const int tid  = threadIdx.x;
    const int w    = tid >> 6;
    const int lane = tid & 63;
    const int quad = lane >> 4;
    const int col  = lane & 15;
    const int cb   = blockIdx.x * CPB;

    __shared__ alignas(16) half_t s_x[2][CPB * HST];
    __shared__ alignas(16) half_t s_h[2][CPB * HST];

    const int rr = w * 16 + col;
    half8 Bxr[4], Bxz[4], Bxn[4];       // Wih (K=128)
    half8 Bhr[4], Bhz[4], Bhn[4];       // Whh (K=128)
#pragma unroll
    for (int s = 0; s < 4; ++s) {
        Bxr[s] = cvt8(Wih + (rr      ) * 128 + s * 32 + quad * 8);
        Bxz[s] = cvt8(Wih + (rr + 128) * 128 + s * 32 + quad * 8);
        Bxn[s] = cvt8(Wih + (rr + 256) * 128 + s * 32 + quad * 8);
        Bhr[s] = cvt8(Whh + (rr      ) * 128 + s * 32 + quad * 8);
        Bhz[s] = cvt8(Whh + (rr + 128) * 128 + s * 32 + quad * 8);
        Bhn[s] = cvt8(Whh + (rr + 256) * 128 + s * 32 + quad * 8);
    }
    const float br  = bih[rr] + bhh[rr];
    const float bz  = bih[128 + rr] + bhh[128 + rr];
    const float bni = bih[256 + rr];
    const float bnh = bhh[256 + rr];

    for (int i = tid; i < CPB * HST; i += 512) s_h[0][i] = (half_t)0.0f;

    // staging: thread -> (chain sm, 4 cols sc4), 8B per thread per step
    const int sm  = tid >> 5;
    const int sc4 = (tid & 31) * 4;
    const half_t* xrow = h1 + (size_t)(cb + sm) * SS * 128 + sc4;
    {   // stage x_0 (= h1[:,0,:])
        uint2 g = *(const uint2*)(xrow);
        *(uint2*)(&s_x[0][sm * HST + sc4]) = g;
    }
    __syncthreads();

    float hp[4] = {0.f, 0.f, 0.f, 0.f};
    const int hcol = w * 16 + col;

    for (int t = 0; t < SS; ++t) {
        const int cur = t & 1, nxt = cur ^ 1;

        uint2 g = {0u, 0u};
        const bool pf = (t + 1 < SS);
        if (pf) g = *(const uint2*)(xrow + (size_t)(t + 1) * 128);

        f32x4 ar  = {br, br, br, br},     az  = {bz, bz, bz, bz};
        f32x4 ani = {bni, bni, bni, bni}, anh = {bnh, bnh, bnh, bnh};
#pragma unroll
        for (int s = 0; s < 4; ++s) {
            half8 ax = *(const half8*)(&s_x[cur][col * HST + s * 32 + quad * 8]);
            half8 ah = *(const half8*)(&s_h[cur][col * HST + s * 32 + quad * 8]);
            ar  = MFMA16(ax, Bxr[s], ar);
            ar  = MFMA16(ah, Bhr[s], ar);
            az  = MFMA16(ax, Bxz[s], az);
            az  = MFMA16(ah, Bhz[s], az);
            ani = MFMA16(ax, Bxn[s], ani);
            anh = MFMA16(ah, Bhn[s], anh);
        }
#pragma unroll
        for (int i = 0; i < 4; ++i) {
            float r = sigmoidf_(ar[i]);
            float z = sigmoidf_(az[i]);
            float n = tanhf_(ani[i] + r * anh[i]);
            float h = (1.0f - z) * n + z * hp[i];
            hp[i] = h;
            s_h[nxt][(quad * 4 + i) * HST + hcol] = (half_t)h;
        }
        if (pf) *(uint2*)(&s_x[nxt][sm * HST + sc4]) = g;
        __syncthreads();
    }

    // FC epilogue: h_final in s_h[0] (SS even). 160 outputs = 16 chains x 10.
    if (tid < 160) {
        const int ch = tid / 10, cl = tid - ch * 10;
        float acc = fcb[cl];
        const float* wr = fcw + cl * 128;
        const half_t* hv = &s_h[0][ch * HST];
#pragma unroll 8
        for (int k = 0; k < 128; ++k) acc += (float)hv[k] * wr[k];
        out[(cb + ch) * 10 + cl] = acc;
    }
}

extern "C" void kernel_launch(void* const* d_in, const int* in_sizes, int n_in,
                              void* d_out, int out_size, void* d_ws, size_t ws_size,
                              hipStream_t stream) {
    const float* x    = (const float*)d_in[0];
    const float* Wih0 = (const float*)d_in[1];
    const float* Whh0 = (const float*)d_in[2];
    const float* bih0 = (const float*)d_in[3];
    const float* bhh0 = (const float*)d_in[4];
    const float* Wih1 = (const float*)d_in[5];
    const float* Whh1 = (const float*)d_in[6];
    const float* bih1 = (const float*)d_in[7];
    const float* bhh1 = (const float*)d_in[8];
    const float* fcw  = (const float*)d_in[9];
    const float* fcb  = (const float*)d_in[10];

    half_t* h1 = (half_t*)d_ws;   // [512,1024,128] f16 = 134 MB

    gru_rec0<<<NBLK, 512, 0, stream>>>(x, Wih0, Whh0, bih0, bhh0, h1);
    gru_rec1<<<NBLK, 512, 0, stream>>>(h1, Wih1, Whh1, bih1, bhh1, fcw, fcb,
                                       (float*)d_out);
}